// Round 5
// baseline (127.168 us; speedup 1.0000x reference)
//
#include <hip/hip_runtime.h>
#include <hip/hip_bf16.h>

#define Bn 16
#define Tn 64
#define Cn 512
#define LDA  520    // bf16 row stride in shorts (pre A tile)
#define LDA8 528    // fp8 row stride in bytes (fused A tile)

#define LOG2E 1.4426950408889634f
#define LN2   0.6931471805599453f
#define ASC 16.0f          // A (relu h) scale, folded into xe / Wt
#define WSC 256.0f         // W_imp scale (lifts out of e4m3 subnormals)
#define ZSC (1.0f/4096.0f) // 1/(ASC*WSC) unscale, folded into sigmoid

typedef short s8v __attribute__((ext_vector_type(8)));          // 8 bf16 frag
typedef float f4v __attribute__((ext_vector_type(4)));          // MFMA acc
typedef unsigned long ul2 __attribute__((ext_vector_type(2)));  // 2 fp8 frags

__device__ __forceinline__ unsigned int pk2bf(float a, float b){
  __hip_bfloat162 t = __float22bfloat162_rn(make_float2(a, b));
  union { __hip_bfloat162 h; unsigned int u; } c; c.h = t; return c.u;
}
__device__ __forceinline__ float bits2f(unsigned int u){
  union { unsigned int u; float f; } c; c.u = u; return c.f;
}
__device__ __forceinline__ s8v pack_bf8(const float* v){
  union { uint4 u; s8v s; } c;
  c.u.x = pk2bf(v[0], v[1]); c.u.y = pk2bf(v[2], v[3]);
  c.u.z = pk2bf(v[4], v[5]); c.u.w = pk2bf(v[6], v[7]);
  return c.s;
}

// ---------------------------------------------------------------------------
// pre: single dispatch, 448 blocks x 256 thr.
//  [0,64):    R table log1p(max(+/-(ts_i-ts_j),0)) -> R;  also zero out1
//  [64,192):  Wi f32 *256 -> fp8 e4m3, lane-contig frag order -> Wsw8
//  [192,448): GEMM blocks (b, mat, oct): self-swizzling B from global W.
//     mat=0: values=x@Wp+bp -> vfrag bf16 *log2e (fused C-frag order)
//     mat=1: xe=(x@Wx+bx+bt)*ASC (f32 row-major)
// ---------------------------------------------------------------------------
__global__ __launch_bounds__(256)
void pre(const float* __restrict__ x, const float* __restrict__ ts,
         const float* __restrict__ Wp, const float* __restrict__ bp,
         const float* __restrict__ Wx, const float* __restrict__ bx,
         const float* __restrict__ bt, const float* __restrict__ Wi,
         float* __restrict__ xe, unsigned short* __restrict__ vfrag,
         unsigned char* __restrict__ Wsw8, float* __restrict__ R,
         float* __restrict__ out1){
  __shared__ unsigned short lA[Tn * LDA];
  const int blk = blockIdx.x;
  const int tid = threadIdx.x;
  if(blk < 64){
    int gid2 = blk * 256 + tid;                      // 16384 threads, 4 pairs each
    float r[8];
#pragma unroll
    for(int q = 0; q < 4; ++q){
      int p = gid2 * 4 + q;
      int b = p >> 12, i = (p >> 6) & 63, j = p & 63;
      float d = ts[b * Tn + i] - ts[b * Tn + j];
      r[2*q]   = __logf(1.f + fmaxf(d, 0.f));
      r[2*q+1] = __logf(1.f + fmaxf(-d, 0.f));
    }
    float4* Rf4 = reinterpret_cast<float4*>(R);
    Rf4[gid2 * 2    ] = make_float4(r[0], r[1], r[2], r[3]);
    Rf4[gid2 * 2 + 1] = make_float4(r[4], r[5], r[6], r[7]);
    // zero-init out1 (fused accumulates into it with atomics): 65536 floats
    reinterpret_cast<float4*>(out1)[gid2] = make_float4(0.f, 0.f, 0.f, 0.f);
    return;
  }
  if(blk < 192){
    int rem = (blk - 64) * 256 + tid;                // 32768 threads
    int nt = rem & 3, lane = (rem >> 2) & 63, w8 = (rem >> 8) & 7, s = rem >> 11;
    int n  = (w8 * 4 + nt) * 16 + (lane & 15);
    int k0 = s * 32 + ((lane >> 4) << 3);
    float v[8];
#pragma unroll
    for(int j = 0; j < 8; ++j) v[j] = Wi[(k0 + j) * Cn + n] * WSC;
    int d0 = __builtin_amdgcn_cvt_pk_fp8_f32(v[0], v[1], 0, false);
    d0     = __builtin_amdgcn_cvt_pk_fp8_f32(v[2], v[3], d0, true);
    int d1 = __builtin_amdgcn_cvt_pk_fp8_f32(v[4], v[5], 0, false);
    d1     = __builtin_amdgcn_cvt_pk_fp8_f32(v[6], v[7], d1, true);
    uint2 o; o.x = (unsigned int)d0; o.y = (unsigned int)d1;
    *reinterpret_cast<uint2*>(Wsw8 + (size_t)((s * 8 + w8) * 64 + lane) * 32 + nt * 8) = o;
    return;
  }
  // ---- GEMM blocks ----
  const int idx = blk - 192;
  const int b = idx >> 4, mat = (idx >> 3) & 1, oct = idx & 7;
  const int lane = tid & 63, w2 = tid >> 6, quad = lane >> 4, ln = lane & 15;
  const int t = oct * 4 + w2;
  const float* Wg = mat ? Wx : Wp;
  const float* wb = Wg + (size_t)(quad * 8) * Cn + t * 16 + ln;

  const int c0 = (tid & 127) * 4, jb = tid >> 7;     // jb in {0,1}
#pragma unroll
  for(int it = 0; it < 32; ++it){
    int j = jb + it * 2;
    f4v xv = *reinterpret_cast<const f4v*>(x + ((b * Tn + j) * Cn + c0));
    uint2 uu; uu.x = pk2bf(xv[0], xv[1]); uu.y = pk2bf(xv[2], xv[3]);
    *reinterpret_cast<uint2*>(&lA[j * LDA + c0]) = uu;
  }
  float wv[8];
#pragma unroll
  for(int j = 0; j < 8; ++j) wv[j] = wb[j * Cn];
  __syncthreads();

  s8v a[4], an[4];
#pragma unroll
  for(int mt = 0; mt < 4; ++mt)
    a[mt] = *reinterpret_cast<const s8v*>(&lA[(mt * 16 + ln) * LDA + quad * 8]);
  f4v acc[4];
#pragma unroll
  for(int mt = 0; mt < 4; ++mt){ acc[mt][0]=0.f; acc[mt][1]=0.f; acc[mt][2]=0.f; acc[mt][3]=0.f; }
  s8v bcur = pack_bf8(wv);

#pragma unroll 2
  for(int s = 0; s < 16; ++s){
    int sn = (s + 1) & 15;
    float wn[8];
#pragma unroll
    for(int j = 0; j < 8; ++j) wn[j] = wb[(size_t)sn * 32 * Cn + j * Cn];
#pragma unroll
    for(int mt = 0; mt < 4; ++mt)
      an[mt] = *reinterpret_cast<const s8v*>(&lA[(mt * 16 + ln) * LDA + sn * 32 + quad * 8]);
#pragma unroll
    for(int mt = 0; mt < 4; ++mt)
      acc[mt] = __builtin_amdgcn_mfma_f32_16x16x32_bf16(a[mt], bcur, acc[mt], 0, 0, 0);
#pragma unroll
    for(int mt = 0; mt < 4; ++mt) a[mt] = an[mt];
    bcur = pack_bf8(wn);
  }

  const int c = t * 16 + ln;
  if(mat == 0){
    float bb = bp[c];
    const int eb_h = w2 & 1;
#pragma unroll
    for(int mt = 0; mt < 4; ++mt){
      float v0 = (acc[mt][0] + bb) * LOG2E;
      float v1 = (acc[mt][1] + bb) * LOG2E;
      float v2 = (acc[mt][2] + bb) * LOG2E;
      float v3 = (acc[mt][3] + bb) * LOG2E;
      uint2 o; o.x = pk2bf(v0, v1); o.y = pk2bf(v2, v3);
      int eb = mt * 2 + (w2 >> 1);
      *reinterpret_cast<uint2*>(vfrag + ((size_t)((b * 8 + oct) * 8 + eb) * 64 + lane) * 8 + eb_h * 4) = o;
    }
  } else {
    float bb = bx[c] + bt[c];
#pragma unroll
    for(int mt = 0; mt < 4; ++mt)
#pragma unroll
      for(int r = 0; r < 4; ++r){
        int j = mt * 16 + quad * 4 + r;
        xe[(b * Tn + j) * Cn + c] = (acc[mt][r] + bb) * ASC;
      }
  }
}

// ---------------------------------------------------------------------------
// fused: TWO blocks per (b,i) — N-split (half = 256 cols), 256 thr / 4 waves.
// 4 independent blocks/CU with K-phases 0/4/8/12 -> deeper MFMA/VALU phase
// decorrelation. A-build duplicated per half (cheap VALU). out0 by column
// (block-local); out1 via global atomicAdd (pre zero-inits; 2 commutative
// adds -> deterministic).
// ---------------------------------------------------------------------------
__global__ __launch_bounds__(256, 4)
void fused(const float* __restrict__ x, const float* __restrict__ am,
           const float* __restrict__ Wt, const float* __restrict__ bimp,
           const unsigned char* __restrict__ Wsw8, const float* __restrict__ R,
           const float* __restrict__ xe, const unsigned short* __restrict__ vfrag,
           float* __restrict__ out0, float* __restrict__ out1){
  __shared__ unsigned char lA8[Tn * LDA8];
  __shared__ float msk[Tn], rr0[Tn], rr1[Tn], rsum[Tn];
  const int bi = blockIdx.x >> 1, half = blockIdx.x & 1;
  const int b = bi >> 6, i = bi & 63;
  const int tid = threadIdx.x;
  const int lane = tid & 63, w = tid >> 6, quad = lane >> 4, ln = lane & 15;
  const int w8 = half * 4 + w;                       // global 64-col chunk
  const int ph = (blockIdx.x & 3) << 2;              // K phases 0/4/8/12

  // small staging loads first
  float mv = 0.f; float2 rv = make_float2(0.f, 0.f);
  if(tid < Tn){
    mv = am[b * Tn + tid];
    rv = reinterpret_cast<const float2*>(R)[(b * Tn + i) * Tn + tid];
  }

  // hoisted xe loads, batch 0 (rows 0..31 for this thread)
  const int c0 = (tid & 127) * 4, jb = tid >> 7;     // jb in {0,1}
  f4v xv[16];
#pragma unroll
  for(int it = 0; it < 16; ++it)
    xv[it] = *reinterpret_cast<const f4v*>(xe + ((b * Tn + (jb + it * 2)) * Cn + c0));

  // hoisted B prefetch for phases ph, ph+1
  const ul2* Bv = reinterpret_cast<const ul2*>(Wsw8);
  const int off = (w8 * 64 + lane) * 2;
  ul2 bA[2], bB[2];
  bA[0] = Bv[ph * 1024 + off];       bB[0] = Bv[ph * 1024 + off + 1];
  bA[1] = Bv[(ph + 1) * 1024 + off]; bB[1] = Bv[(ph + 1) * 1024 + off + 1];

  if(tid < Tn){ msk[tid] = mv; rr0[tid] = rv.x; rr1[tid] = rv.y; rsum[tid] = 0.f; }

  f4v wt0 = *reinterpret_cast<const f4v*>(Wt + c0);
  f4v wt1 = *reinterpret_cast<const f4v*>(Wt + Cn + c0);
  wt0[0]*=ASC; wt0[1]*=ASC; wt0[2]*=ASC; wt0[3]*=ASC;   // xe already x16
  wt1[0]*=ASC; wt1[1]*=ASC; wt1[2]*=ASC; wt1[3]*=ASC;

#pragma unroll
  for(int it = 0; it < 16; ++it){
    int j = jb + it * 2;
    float r0 = rr0[j], r1 = rr1[j];
    float h0 = fmaxf(fmaf(r1, wt1[0], fmaf(r0, wt0[0], xv[it][0])), 0.f);
    float h1 = fmaxf(fmaf(r1, wt1[1], fmaf(r0, wt0[1], xv[it][1])), 0.f);
    float h2 = fmaxf(fmaf(r1, wt1[2], fmaf(r0, wt0[2], xv[it][2])), 0.f);
    float h3 = fmaxf(fmaf(r1, wt1[3], fmaf(r0, wt0[3], xv[it][3])), 0.f);
    int d = __builtin_amdgcn_cvt_pk_fp8_f32(h0, h1, 0, false);
    d     = __builtin_amdgcn_cvt_pk_fp8_f32(h2, h3, d, true);
    *reinterpret_cast<int*>(lA8 + j * LDA8 + c0) = d;
  }
  // batch 1 (rows 32..63)
#pragma unroll
  for(int it = 0; it < 16; ++it)
    xv[it] = *reinterpret_cast<const f4v*>(xe + ((b * Tn + (32 + jb + it * 2)) * Cn + c0));
#pragma unroll
  for(int it = 0; it < 16; ++it){
    int j = 32 + jb + it * 2;
    float r0 = rr0[j], r1 = rr1[j];
    float h0 = fmaxf(fmaf(r1, wt1[0], fmaf(r0, wt0[0], xv[it][0])), 0.f);
    float h1 = fmaxf(fmaf(r1, wt1[1], fmaf(r0, wt0[1], xv[it][1])), 0.f);
    float h2 = fmaxf(fmaf(r1, wt1[2], fmaf(r0, wt0[2], xv[it][2])), 0.f);
    float h3 = fmaxf(fmaf(r1, wt1[3], fmaf(r0, wt0[3], xv[it][3])), 0.f);
    int d = __builtin_amdgcn_cvt_pk_fp8_f32(h0, h1, 0, false);
    d     = __builtin_amdgcn_cvt_pk_fp8_f32(h2, h3, d, true);
    *reinterpret_cast<int*>(lA8 + j * LDA8 + c0) = d;
  }
  __syncthreads();

  unsigned long a[4], an[4];
#pragma unroll
  for(int mt = 0; mt < 4; ++mt)
    a[mt] = *reinterpret_cast<const unsigned long*>(lA8 + (mt * 16 + ln) * LDA8 + ph * 32 + quad * 8);
  f4v acc[4][4];
#pragma unroll
  for(int mt = 0; mt < 4; ++mt)
#pragma unroll
    for(int nt = 0; nt < 4; ++nt){
      acc[mt][nt][0]=0.f; acc[mt][nt][1]=0.f; acc[mt][nt][2]=0.f; acc[mt][nt][3]=0.f;
    }

#pragma unroll 2
  for(int s = 0; s < 16; ++s){
    const int sc = s & 1;
    const int p2 = (s + 2 + ph) & 15;                // B prefetch, depth 2
    const int p1 = (s + 1 + ph) & 15;                // A prefetch, depth 1
    ul2 nb0 = Bv[p2 * 1024 + off];
    ul2 nb1 = Bv[p2 * 1024 + off + 1];
#pragma unroll
    for(int mt = 0; mt < 4; ++mt)
      an[mt] = *reinterpret_cast<const unsigned long*>(lA8 + (mt * 16 + ln) * LDA8 + p1 * 32 + quad * 8);
    long bf0 = (long)bA[sc].x, bf1 = (long)bA[sc].y;
    long bf2 = (long)bB[sc].x, bf3 = (long)bB[sc].y;
#pragma unroll
    for(int mt = 0; mt < 4; ++mt){
      acc[mt][0] = __builtin_amdgcn_mfma_f32_16x16x32_fp8_fp8((long)a[mt], bf0, acc[mt][0], 0, 0, 0);
      acc[mt][1] = __builtin_amdgcn_mfma_f32_16x16x32_fp8_fp8((long)a[mt], bf1, acc[mt][1], 0, 0, 0);
      acc[mt][2] = __builtin_amdgcn_mfma_f32_16x16x32_fp8_fp8((long)a[mt], bf2, acc[mt][2], 0, 0, 0);
      acc[mt][3] = __builtin_amdgcn_mfma_f32_16x16x32_fp8_fp8((long)a[mt], bf3, acc[mt][3], 0, 0, 0);
    }
#pragma unroll
    for(int mt = 0; mt < 4; ++mt) a[mt] = an[mt];
    bA[sc] = nb0; bB[sc] = nb1;
  }

  // values (bf16, pre-scaled by log2e), fragment order: 8 coalesced 16B loads
  uint4 vv[8];
#pragma unroll
  for(int eb = 0; eb < 8; ++eb)
    vv[eb] = *reinterpret_cast<const uint4*>(vfrag + ((size_t)((b * 8 + w8) * 8 + eb) * 64 + lane) * 8);
  // x values for the out0 epilogue (quad 0 lanes write)
  float xq[4];
#pragma unroll
  for(int nt = 0; nt < 4; ++nt)
    xq[nt] = x[(b * Tn + i) * Cn + (w8 * 64 + nt * 16 + ln)];

  // sigmoid (with 1/4096 unscale) + mask, fused with out1 rowsum partial
  float bb[4];
#pragma unroll
  for(int nt = 0; nt < 4; ++nt) bb[nt] = bimp[w8 * 64 + nt * 16 + ln];
#pragma unroll
  for(int mt = 0; mt < 4; ++mt)
#pragma unroll
    for(int r = 0; r < 4; ++r){
      float mk = msk[mt * 16 + quad * 4 + r];
      float p = 0.f;
#pragma unroll
      for(int nt = 0; nt < 4; ++nt){
        float z = fmaf(acc[mt][nt][r], ZSC, bb[nt]);
        float im = mk * __builtin_amdgcn_rcpf(1.f + __builtin_amdgcn_exp2f(z * -LOG2E));
        acc[mt][nt][r] = im;
        p += im;
      }
      p += __shfl_xor(p, 1, 64);
      p += __shfl_xor(p, 2, 64);
      p += __shfl_xor(p, 4, 64);
      p += __shfl_xor(p, 8, 64);
      if(ln == 0) atomicAdd(&rsum[mt * 16 + quad * 4 + r], p);
    }
  __syncthreads();
  if(tid < Tn) atomicAdd(&out1[(b * Tn + i) * Tn + tid], rsum[tid] * (1.f / 512.f));

  // logsumexp over j: se = sum exp2(vl * imp), vl = values*log2e
  const unsigned int* vw = reinterpret_cast<const unsigned int*>(vv);
#pragma unroll
  for(int nt = 0; nt < 4; ++nt){
    float se = 0.f;
#pragma unroll
    for(int mt = 0; mt < 4; ++mt)
#pragma unroll
      for(int r = 0; r < 4; ++r){
        int e = mt * 16 + nt * 4 + r;
        unsigned int d = vw[e >> 1];
        float vl = bits2f((e & 1) ? (d & 0xffff0000u) : (d << 16));
        se += __builtin_amdgcn_exp2f(vl * acc[mt][nt][r]);
      }
    se += __shfl_xor(se, 16, 64);
    se += __shfl_xor(se, 32, 64);
    if(quad == 0){
      int idx = (b * Tn + i) * Cn + (w8 * 64 + nt * 16 + ln);
      out0[idx] = xq[nt] + __builtin_amdgcn_logf(se) * LN2;
    }
  }
}

extern "C" void kernel_launch(void* const* d_in, const int* in_sizes, int n_in,
                              void* d_out, int out_size, void* d_ws, size_t ws_size,
                              hipStream_t stream){
  const float* x    = (const float*)d_in[0];
  const float* ts   = (const float*)d_in[1];
  const float* am   = (const float*)d_in[2];
  const float* Wp   = (const float*)d_in[3];
  const float* bp   = (const float*)d_in[4];
  const float* Wx   = (const float*)d_in[5];
  const float* bx   = (const float*)d_in[6];
  const float* Wt   = (const float*)d_in[7];
  const float* bt   = (const float*)d_in[8];
  const float* Wi   = (const float*)d_in[9];
  const float* bimp = (const float*)d_in[10];
  float* out0 = (float*)d_out;
  float* out1 = out0 + Bn * Tn * Cn;

  char* ws = (char*)d_ws;
  unsigned char*  Wsw8  = (unsigned char*)ws;                   // 256KB: Wi fp8 frags
  float*          xe    = (float*)(ws + 262144);                // 2MB f32 (scaled x16)
  unsigned short* vfrag = (unsigned short*)(ws + 2359296);      // 1MB bf16 frag-order
  float*          R     = (float*)(ws + 3407872);               // 512KB log1p table

  pre<<<448, 256, 0, stream>>>(x, ts, Wp, bp, Wx, bx, bt, Wi, xe, vfrag, Wsw8, R, out1);
  fused<<<2048, 256, 0, stream>>>(x, am, Wt, bimp, Wsw8, R, xe, vfrag, out0, out1);
}

// Round 6
// 124.858 us; speedup vs baseline: 1.0185x; 1.0185x over previous
//
#include <hip/hip_runtime.h>
#include <hip/hip_bf16.h>

#define Bn 16
#define Tn 64
#define Cn 512
#define LDA  520    // bf16 row stride in shorts (pre A tile)
#define LDA8 528    // fp8 row stride in bytes (fused A tile)

#define LOG2E 1.4426950408889634f
#define LN2   0.6931471805599453f
#define ASC 16.0f          // A (relu h) scale, folded into xe / Wt
#define WSC 256.0f         // W_imp scale (lifts out of e4m3 subnormals)
#define ZSC (1.0f/4096.0f) // 1/(ASC*WSC) unscale
#define NZL (-(LOG2E)*(ZSC)) // folded -log2e/4096 for sigmoid arg

typedef short s8v __attribute__((ext_vector_type(8)));          // 8 bf16 frag
typedef float f4v __attribute__((ext_vector_type(4)));          // MFMA acc
typedef unsigned long ul2 __attribute__((ext_vector_type(2)));  // 2 fp8 frags

__device__ __forceinline__ unsigned int pk2bf(float a, float b){
  __hip_bfloat162 t = __float22bfloat162_rn(make_float2(a, b));
  union { __hip_bfloat162 h; unsigned int u; } c; c.h = t; return c.u;
}
__device__ __forceinline__ float bits2f(unsigned int u){
  union { unsigned int u; float f; } c; c.u = u; return c.f;
}
__device__ __forceinline__ s8v pack_bf8(const float* v){
  union { uint4 u; s8v s; } c;
  c.u.x = pk2bf(v[0], v[1]); c.u.y = pk2bf(v[2], v[3]);
  c.u.z = pk2bf(v[4], v[5]); c.u.w = pk2bf(v[6], v[7]);
  return c.s;
}

// ---------------------------------------------------------------------------
// pre: single dispatch, 448 blocks x 256 thr.
//  [0,64):    R table log1p(max(+/-(ts_i-ts_j),0)) -> R
//  [64,192):  Wi f32 *256 -> fp8 e4m3, lane-contig frag order -> Wsw8
//  [192,448): GEMM blocks (b, mat, oct): self-swizzling B from global W.
//     mat=0: values=x@Wp+bp -> vfrag bf16 *log2e (fused C-frag order)
//     mat=1: xe=(x@Wx+bx+bt)*ASC (f32 row-major)
// ---------------------------------------------------------------------------
__global__ __launch_bounds__(256)
void pre(const float* __restrict__ x, const float* __restrict__ ts,
         const float* __restrict__ Wp, const float* __restrict__ bp,
         const float* __restrict__ Wx, const float* __restrict__ bx,
         const float* __restrict__ bt, const float* __restrict__ Wi,
         float* __restrict__ xe, unsigned short* __restrict__ vfrag,
         unsigned char* __restrict__ Wsw8, float* __restrict__ R){
  __shared__ unsigned short lA[Tn * LDA];
  const int blk = blockIdx.x;
  const int tid = threadIdx.x;
  if(blk < 64){
    int gid2 = blk * 256 + tid;                      // 16384 threads, 4 pairs each
    float r[8];
#pragma unroll
    for(int q = 0; q < 4; ++q){
      int p = gid2 * 4 + q;
      int b = p >> 12, i = (p >> 6) & 63, j = p & 63;
      float d = ts[b * Tn + i] - ts[b * Tn + j];
      r[2*q]   = __logf(1.f + fmaxf(d, 0.f));
      r[2*q+1] = __logf(1.f + fmaxf(-d, 0.f));
    }
    float4* Rf4 = reinterpret_cast<float4*>(R);
    Rf4[gid2 * 2    ] = make_float4(r[0], r[1], r[2], r[3]);
    Rf4[gid2 * 2 + 1] = make_float4(r[4], r[5], r[6], r[7]);
    return;
  }
  if(blk < 192){
    int rem = (blk - 64) * 256 + tid;                // 32768 threads
    int nt = rem & 3, lane = (rem >> 2) & 63, w8 = (rem >> 8) & 7, s = rem >> 11;
    int n  = (w8 * 4 + nt) * 16 + (lane & 15);
    int k0 = s * 32 + ((lane >> 4) << 3);
    float v[8];
#pragma unroll
    for(int j = 0; j < 8; ++j) v[j] = Wi[(k0 + j) * Cn + n] * WSC;
    int d0 = __builtin_amdgcn_cvt_pk_fp8_f32(v[0], v[1], 0, false);
    d0     = __builtin_amdgcn_cvt_pk_fp8_f32(v[2], v[3], d0, true);
    int d1 = __builtin_amdgcn_cvt_pk_fp8_f32(v[4], v[5], 0, false);
    d1     = __builtin_amdgcn_cvt_pk_fp8_f32(v[6], v[7], d1, true);
    uint2 o; o.x = (unsigned int)d0; o.y = (unsigned int)d1;
    *reinterpret_cast<uint2*>(Wsw8 + (size_t)((s * 8 + w8) * 64 + lane) * 32 + nt * 8) = o;
    return;
  }
  // ---- GEMM blocks ----
  const int idx = blk - 192;
  const int b = idx >> 4, mat = (idx >> 3) & 1, oct = idx & 7;
  const int lane = tid & 63, w2 = tid >> 6, quad = lane >> 4, ln = lane & 15;
  const int t = oct * 4 + w2;
  const float* Wg = mat ? Wx : Wp;
  const float* wb = Wg + (size_t)(quad * 8) * Cn + t * 16 + ln;

  const int c0 = (tid & 127) * 4, jb = tid >> 7;     // jb in {0,1}
#pragma unroll
  for(int it = 0; it < 32; ++it){
    int j = jb + it * 2;
    f4v xv = *reinterpret_cast<const f4v*>(x + ((b * Tn + j) * Cn + c0));
    uint2 uu; uu.x = pk2bf(xv[0], xv[1]); uu.y = pk2bf(xv[2], xv[3]);
    *reinterpret_cast<uint2*>(&lA[j * LDA + c0]) = uu;
  }
  float wv[8];
#pragma unroll
  for(int j = 0; j < 8; ++j) wv[j] = wb[j * Cn];
  __syncthreads();

  s8v a[4], an[4];
#pragma unroll
  for(int mt = 0; mt < 4; ++mt)
    a[mt] = *reinterpret_cast<const s8v*>(&lA[(mt * 16 + ln) * LDA + quad * 8]);
  f4v acc[4];
#pragma unroll
  for(int mt = 0; mt < 4; ++mt){ acc[mt][0]=0.f; acc[mt][1]=0.f; acc[mt][2]=0.f; acc[mt][3]=0.f; }
  s8v bcur = pack_bf8(wv);

#pragma unroll 2
  for(int s = 0; s < 16; ++s){
    int sn = (s + 1) & 15;
    float wn[8];
#pragma unroll
    for(int j = 0; j < 8; ++j) wn[j] = wb[(size_t)sn * 32 * Cn + j * Cn];
#pragma unroll
    for(int mt = 0; mt < 4; ++mt)
      an[mt] = *reinterpret_cast<const s8v*>(&lA[(mt * 16 + ln) * LDA + sn * 32 + quad * 8]);
#pragma unroll
    for(int mt = 0; mt < 4; ++mt)
      acc[mt] = __builtin_amdgcn_mfma_f32_16x16x32_bf16(a[mt], bcur, acc[mt], 0, 0, 0);
#pragma unroll
    for(int mt = 0; mt < 4; ++mt) a[mt] = an[mt];
    bcur = pack_bf8(wn);
  }

  const int c = t * 16 + ln;
  if(mat == 0){
    float bb = bp[c];
    const int eb_h = w2 & 1;
#pragma unroll
    for(int mt = 0; mt < 4; ++mt){
      float v0 = (acc[mt][0] + bb) * LOG2E;
      float v1 = (acc[mt][1] + bb) * LOG2E;
      float v2 = (acc[mt][2] + bb) * LOG2E;
      float v3 = (acc[mt][3] + bb) * LOG2E;
      uint2 o; o.x = pk2bf(v0, v1); o.y = pk2bf(v2, v3);
      int eb = mt * 2 + (w2 >> 1);
      *reinterpret_cast<uint2*>(vfrag + ((size_t)((b * 8 + oct) * 8 + eb) * 64 + lane) * 8 + eb_h * 4) = o;
    }
  } else {
    float bb = bx[c] + bt[c];
#pragma unroll
    for(int mt = 0; mt < 4; ++mt)
#pragma unroll
      for(int r = 0; r < 4; ++r){
        int j = mt * 16 + quad * 4 + r;
        xe[(b * Tn + j) * Cn + c] = (acc[mt][r] + bb) * ASC;
      }
  }
}

// ---------------------------------------------------------------------------
// fused (round-4 structure + VALU cuts): one 512-thr block per (b,i).
// Hoisted xe/B loads above barrier; B prefetch depth 2; K phase rotation by
// block parity; unroll-4 K-loop (register renaming kills rotation movs);
// merged sigmoid+LSE epilogue with folded constants.
// ---------------------------------------------------------------------------
__global__ __launch_bounds__(512, 4)
void fused(const float* __restrict__ x, const float* __restrict__ am,
           const float* __restrict__ Wt, const float* __restrict__ bimp,
           const unsigned char* __restrict__ Wsw8, const float* __restrict__ R,
           const float* __restrict__ xe, const unsigned short* __restrict__ vfrag,
           float* __restrict__ out0, float* __restrict__ out1){
  __shared__ unsigned char lA8[Tn * LDA8];
  __shared__ float msk[Tn], rr0[Tn], rr1[Tn], rsum[Tn];
  const int b = blockIdx.x >> 6, i = blockIdx.x & 63;
  const int tid = threadIdx.x;
  const int lane = tid & 63, w = tid >> 6, quad = lane >> 4, ln = lane & 15;
  const int ph = (blockIdx.x & 1) << 3;              // K-loop phase 0 / 8

  // small staging loads first
  float mv = 0.f; float2 rv = make_float2(0.f, 0.f);
  if(tid < Tn){
    mv = am[b * Tn + tid];
    rv = reinterpret_cast<const float2*>(R)[(b * Tn + i) * Tn + tid];
  }

  // hoisted xe loads: in flight across the staging barrier
  const int c0 = (tid & 127) * 4, jb = tid >> 7;
  f4v xv[16];
#pragma unroll
  for(int it = 0; it < 16; ++it)
    xv[it] = *reinterpret_cast<const f4v*>(xe + ((b * Tn + (jb + it * 4)) * Cn + c0));

  // hoisted B prefetch for phases ph, ph+1
  const ul2* Bv = reinterpret_cast<const ul2*>(Wsw8);
  const int off = (w * 64 + lane) * 2;
  ul2 bA[2], bB[2];
  bA[0] = Bv[ph * 1024 + off];       bB[0] = Bv[ph * 1024 + off + 1];
  bA[1] = Bv[(ph + 1) * 1024 + off]; bB[1] = Bv[(ph + 1) * 1024 + off + 1];

  if(tid < Tn){ msk[tid] = mv; rr0[tid] = rv.x; rr1[tid] = rv.y; rsum[tid] = 0.f; }
  __syncthreads();

  f4v wt0 = *reinterpret_cast<const f4v*>(Wt + c0);
  f4v wt1 = *reinterpret_cast<const f4v*>(Wt + Cn + c0);
  wt0[0]*=ASC; wt0[1]*=ASC; wt0[2]*=ASC; wt0[3]*=ASC;   // xe already x16
  wt1[0]*=ASC; wt1[1]*=ASC; wt1[2]*=ASC; wt1[3]*=ASC;
#pragma unroll
  for(int it = 0; it < 16; ++it){
    int j = jb + it * 4;
    float r0 = rr0[j], r1 = rr1[j];
    float h0 = fmaxf(fmaf(r1, wt1[0], fmaf(r0, wt0[0], xv[it][0])), 0.f);
    float h1 = fmaxf(fmaf(r1, wt1[1], fmaf(r0, wt0[1], xv[it][1])), 0.f);
    float h2 = fmaxf(fmaf(r1, wt1[2], fmaf(r0, wt0[2], xv[it][2])), 0.f);
    float h3 = fmaxf(fmaf(r1, wt1[3], fmaf(r0, wt0[3], xv[it][3])), 0.f);
    int d = __builtin_amdgcn_cvt_pk_fp8_f32(h0, h1, 0, false);
    d     = __builtin_amdgcn_cvt_pk_fp8_f32(h2, h3, d, true);
    *reinterpret_cast<int*>(lA8 + j * LDA8 + c0) = d;
  }
  __syncthreads();

  unsigned long a[4], an[4];
#pragma unroll
  for(int mt = 0; mt < 4; ++mt)
    a[mt] = *reinterpret_cast<const unsigned long*>(lA8 + (mt * 16 + ln) * LDA8 + ph * 32 + quad * 8);
  f4v acc[4][4];
#pragma unroll
  for(int mt = 0; mt < 4; ++mt)
#pragma unroll
    for(int nt = 0; nt < 4; ++nt){
      acc[mt][nt][0]=0.f; acc[mt][nt][1]=0.f; acc[mt][nt][2]=0.f; acc[mt][nt][3]=0.f;
    }

#pragma unroll 4
  for(int s = 0; s < 16; ++s){
    const int sc = s & 1;
    const int p2 = (s + 2 + ph) & 15;                // B prefetch, depth 2
    const int p1 = (s + 1 + ph) & 15;                // A prefetch, depth 1
    ul2 nb0 = Bv[p2 * 1024 + off];
    ul2 nb1 = Bv[p2 * 1024 + off + 1];
#pragma unroll
    for(int mt = 0; mt < 4; ++mt)
      an[mt] = *reinterpret_cast<const unsigned long*>(lA8 + (mt * 16 + ln) * LDA8 + p1 * 32 + quad * 8);
    long bf0 = (long)bA[sc].x, bf1 = (long)bA[sc].y;
    long bf2 = (long)bB[sc].x, bf3 = (long)bB[sc].y;
#pragma unroll
    for(int mt = 0; mt < 4; ++mt){
      acc[mt][0] = __builtin_amdgcn_mfma_f32_16x16x32_fp8_fp8((long)a[mt], bf0, acc[mt][0], 0, 0, 0);
      acc[mt][1] = __builtin_amdgcn_mfma_f32_16x16x32_fp8_fp8((long)a[mt], bf1, acc[mt][1], 0, 0, 0);
      acc[mt][2] = __builtin_amdgcn_mfma_f32_16x16x32_fp8_fp8((long)a[mt], bf2, acc[mt][2], 0, 0, 0);
      acc[mt][3] = __builtin_amdgcn_mfma_f32_16x16x32_fp8_fp8((long)a[mt], bf3, acc[mt][3], 0, 0, 0);
    }
#pragma unroll
    for(int mt = 0; mt < 4; ++mt) a[mt] = an[mt];
    bA[sc] = nb0; bB[sc] = nb1;
  }

  // values (bf16, pre-scaled by log2e), frag order: 8 coalesced 16B loads
  uint4 vv[8];
#pragma unroll
  for(int eb = 0; eb < 8; ++eb)
    vv[eb] = *reinterpret_cast<const uint4*>(vfrag + ((size_t)((b * 8 + w) * 8 + eb) * 64 + lane) * 8);
  // x for the out0 epilogue — hoisted so latency hides under the trans loop
  float xq[4];
#pragma unroll
  for(int nt = 0; nt < 4; ++nt)
    xq[nt] = x[(b * Tn + i) * Cn + (w * 64 + nt * 16 + ln)];

  // merged epilogue: sigmoid (folded -log2e/4096 + bias) + out1 rowsum + LSE
  const unsigned int* vw = reinterpret_cast<const unsigned int*>(vv);
  float bbf[4];
#pragma unroll
  for(int nt = 0; nt < 4; ++nt) bbf[nt] = bimp[w * 64 + nt * 16 + ln] * -LOG2E;
  float se[4] = {0.f, 0.f, 0.f, 0.f};
#pragma unroll
  for(int mt = 0; mt < 4; ++mt)
#pragma unroll
    for(int r = 0; r < 4; ++r){
      float mk = msk[mt * 16 + quad * 4 + r];
      float p = 0.f;
#pragma unroll
      for(int nt = 0; nt < 4; ++nt){
        float zn = fmaf(acc[mt][nt][r], NZL, bbf[nt]);   // = -log2e * (z)
        float im = mk * __builtin_amdgcn_rcpf(1.f + __builtin_amdgcn_exp2f(zn));
        p += im;
        int e = mt * 16 + nt * 4 + r;
        unsigned int d = vw[e >> 1];
        float vl = bits2f((e & 1) ? (d & 0xffff0000u) : (d << 16));
        se[nt] += __builtin_amdgcn_exp2f(vl * im);
      }
      p += __shfl_xor(p, 1, 64);
      p += __shfl_xor(p, 2, 64);
      p += __shfl_xor(p, 4, 64);
      p += __shfl_xor(p, 8, 64);
      if(ln == 0) atomicAdd(&rsum[mt * 16 + quad * 4 + r], p);
    }
  __syncthreads();
  if(tid < Tn) out1[(b * Tn + i) * Tn + tid] = rsum[tid] * (1.f / 512.f);

#pragma unroll
  for(int nt = 0; nt < 4; ++nt){
    float s0 = se[nt];
    s0 += __shfl_xor(s0, 16, 64);
    s0 += __shfl_xor(s0, 32, 64);
    if(quad == 0){
      int idx = (b * Tn + i) * Cn + (w * 64 + nt * 16 + ln);
      out0[idx] = xq[nt] + __builtin_amdgcn_logf(s0) * LN2;
    }
  }
}

extern "C" void kernel_launch(void* const* d_in, const int* in_sizes, int n_in,
                              void* d_out, int out_size, void* d_ws, size_t ws_size,
                              hipStream_t stream){
  const float* x    = (const float*)d_in[0];
  const float* ts   = (const float*)d_in[1];
  const float* am   = (const float*)d_in[2];
  const float* Wp   = (const float*)d_in[3];
  const float* bp   = (const float*)d_in[4];
  const float* Wx   = (const float*)d_in[5];
  const float* bx   = (const float*)d_in[6];
  const float* Wt   = (const float*)d_in[7];
  const float* bt   = (const float*)d_in[8];
  const float* Wi   = (const float*)d_in[9];
  const float* bimp = (const float*)d_in[10];
  float* out0 = (float*)d_out;
  float* out1 = out0 + Bn * Tn * Cn;

  char* ws = (char*)d_ws;
  unsigned char*  Wsw8  = (unsigned char*)ws;                   // 256KB: Wi fp8 frags
  float*          xe    = (float*)(ws + 262144);                // 2MB f32 (scaled x16)
  unsigned short* vfrag = (unsigned short*)(ws + 2359296);      // 1MB bf16 frag-order
  float*          R     = (float*)(ws + 3407872);               // 512KB log1p table

  pre<<<448, 256, 0, stream>>>(x, ts, Wp, bp, Wx, bx, bt, Wi, xe, vfrag, Wsw8, R);
  fused<<<1024, 512, 0, stream>>>(x, am, Wt, bimp, Wsw8, R, xe, vfrag, out0, out1);
}